// Round 11
// baseline (77.017 us; speedup 1.0000x reference)
//
#include <hip/hip_runtime.h>

typedef _Float16 f16;
typedef _Float16 f16x2 __attribute__((ext_vector_type(2)));
typedef _Float16 f16x8 __attribute__((ext_vector_type(8)));
typedef float f32x4 __attribute__((ext_vector_type(4)));
typedef float f32x16 __attribute__((ext_vector_type(16)));

#define MFMA32(A, B, C) __builtin_amdgcn_mfma_f32_32x32x16_f16((A), (B), (C), 0, 0, 0)

static __device__ __forceinline__ float cvt2f(float a, float b) {
    // v_cvt_pkrtz_f16_f32 packed into one 32-bit word
    return __builtin_bit_cast(float, __builtin_amdgcn_cvt_pkrtz(a, b));
}

// B=4, N=512, X_DIM=64, T_DIM=32, H=128
// Block 256 (4 waves), tile 32i x 64j, grid (8,16,4). Per chunk: 1 i-row x 64 j.
// 32x32x16 MFMA (96/chunk vs 192 16x16): tests the per-wave MFMA-feed hypothesis
// (r8/r9/r10 identical at 63.5us; per-wave pipe feed ~14% with 16x16; HK/AITER use
// 32x32 and reach ~31%/wave). C/D layout (verified): col=l&31, row=(r&3)+8(r>>2)+4hi.
// C->B-frag conversion via cvt_pkrtz pairs + shfl_xor(32) half swap.
// A/B frags: lane l holds slot k = 8*(l>>5)+e; A row / B col = l&31 (pre-swizzled
// both sides with the same map -> pairing-symmetric, any consistent map correct).
// y staged in B-frag order (conflict-free lane-linear reads). Full-wave stores.
// launch_bounds(256,1): (256,2)'s 128 cap = HBM scratch spill. Tripwire: FETCH >> 3MB.

__global__ __launch_bounds__(256, 1)
void pairmlp_kernel(const float* __restrict__ x, const float* __restrict__ y,
                    const float* __restrict__ t, const float* __restrict__ W1,
                    const float* __restrict__ b1, const float* __restrict__ W2,
                    const float* __restrict__ b2, const float* __restrict__ W3,
                    const float* __restrict__ b3, float* __restrict__ out)
{
    const int N = 512, H = 128, XD = 64, TD = 32;

    __shared__ f16x8 W1a[1024];   // 16 KB: [(a*4+s)*64+l]: W1[16s+8*(l>>5)+e][32a+(l&31)]
    __shared__ f16x8 W2a[2048];   // 32 KB: [(a*8+s)*64+l]: W2[16s+8*(l>>5)+e][32a+(l&31)]
    __shared__ f16x8 yt[512];     //  8 KB: [(m*4+s)*64+l]: y[jb+32m+(l&31)][16s+8*(l>>5)+e]
    __shared__ f16x8 xt[256];     //  4 KB: [i*8+q]: x[ib+i][8q+e]
    __shared__ f16x8 tbf[16];     // 256 B: [hi*8+sp][e] = (t@W1[64:]+b1)[16sp+8hi+e]

    const int tid = threadIdx.x;
    const int b = blockIdx.z;
    const int ibase = blockIdx.y * 32;
    const int jbase = blockIdx.x * 64;

    // ---------------- staging ----------------
    for (int o = tid; o < 1024; o += 256) {
        int l_ = o & 63, grp = o >> 6, a = grp >> 2, s = grp & 3;
        int h = 32 * a + (l_ & 31), d0 = 16 * s + 8 * (l_ >> 5);
        f16x8 v;
#pragma unroll
        for (int e = 0; e < 8; ++e) v[e] = (f16)W1[(d0 + e) * H + h];
        W1a[o] = v;
    }
    for (int o = tid; o < 2048; o += 256) {
        int l_ = o & 63, grp = o >> 6, a = grp >> 3, s = grp & 7;
        int hp = 32 * a + (l_ & 31), h0 = 16 * s + 8 * (l_ >> 5);
        f16x8 v;
#pragma unroll
        for (int e = 0; e < 8; ++e) v[e] = (f16)W2[(h0 + e) * H + hp];
        W2a[o] = v;
    }
    for (int o = tid; o < 512; o += 256) {
        int l_ = o & 63, grp = o >> 6, m = grp >> 2, s = grp & 3;
        int j = jbase + 32 * m + (l_ & 31), d0 = 16 * s + 8 * (l_ >> 5);
        const float* yp = y + (size_t)(b * N + j) * XD + d0;
        f16x8 v;
#pragma unroll
        for (int e = 0; e < 8; ++e) v[e] = (f16)yp[e];
        yt[o] = v;
    }
    {
        int o = tid, i = o >> 3, q = o & 7;
        const float* xp = x + (size_t)(b * N + ibase + i) * XD + q * 8;
        f16x8 v;
#pragma unroll
        for (int e = 0; e < 8; ++e) v[e] = (f16)xp[e];
        xt[o] = v;
    }
    if (tid < 16) {
        int hi_ = tid >> 3, sp = tid & 7;
        f16x8 v;
#pragma unroll
        for (int e = 0; e < 8; ++e) {
            int h = 16 * sp + 8 * hi_ + e;
            float s = b1[h];
            for (int d = 0; d < TD; ++d)
                s += t[b * TD + d] * W1[(XD + d) * H + h];
            v[e] = (f16)s;
        }
        tbf[tid] = v;
    }
    __syncthreads();

    const int w = tid >> 6;
    const int l = tid & 63;
    const int c = l & 31;
    const int hi = l >> 5;
    const float b3v = b3[0];

    // permanent L3 tables: reg-pair q of C/D covers rows (prow(q), prow(q)+1)+4hi+32a'
    f16x2 b2p[4][8], w3p[4][8];   // 64 regs
#pragma unroll
    for (int a = 0; a < 4; ++a)
#pragma unroll
        for (int q = 0; q < 8; ++q) {
            int h0 = 32 * a + 2 * (q & 1) + 8 * ((q >> 1) & 1) + 16 * (q >> 2) + 4 * hi;
            b2p[a][q] = f16x2{(f16)b2[h0], (f16)b2[h0 + 1]};
            w3p[a][q] = f16x2{(f16)W3[h0], (f16)W3[h0 + 1]};
        }

    const f32x16 zc16 = {};
    const f16x8 z8 = f16x8{};
    const f16x2 z2 = f16x2{};

#pragma unroll 1
    for (int ci = 0; ci < 8; ++ci) {
        const int il = w * 8 + ci;

        // x octets (2-addr broadcast) and diff^2 B-frags
        f16x8 xs[4];
#pragma unroll
        for (int s = 0; s < 4; ++s) xs[s] = xt[il * 8 + 2 * s + hi];
        f16x8 df[4][2];
#pragma unroll
        for (int s = 0; s < 4; ++s)
#pragma unroll
            for (int m = 0; m < 2; ++m) {
                f16x8 yv = yt[(m * 4 + s) * 64 + l];
                f16x8 dd = xs[s] - yv;
                df[s][m] = dd * dd;
            }

        // ---- layer 1 (32 MFMA) in two a-halves; cvt each half into bf2 ----
        f16x8 bf2[8][2];   // [sp][m] B-frags for layer 2
#pragma unroll
        for (int ah = 0; ah < 2; ++ah) {
            f32x16 acc1[2][2];
#pragma unroll
            for (int s = 0; s < 4; ++s)
#pragma unroll
                for (int aa = 0; aa < 2; ++aa) {
                    f16x8 Af = W1a[((ah * 2 + aa) * 4 + s) * 64 + l];
#pragma unroll
                    for (int m = 0; m < 2; ++m) {
                        if (s == 0) acc1[aa][m] = MFMA32(Af, df[s][m], zc16);
                        else        acc1[aa][m] = MFMA32(Af, df[s][m], acc1[aa][m]);
                    }
                }
            // C/D -> B-frag: pack pairs, swap halves, select, bias+relu
#pragma unroll
            for (int aa = 0; aa < 2; ++aa) {
                int a = ah * 2 + aa;
#pragma unroll
                for (int kg = 0; kg < 2; ++kg) {
                    int sp = 2 * a + kg;
                    f16x8 tb8 = tbf[hi * 8 + sp];
#pragma unroll
                    for (int m = 0; m < 2; ++m) {
                        float P0 = cvt2f(acc1[aa][m][8 * kg + 0], acc1[aa][m][8 * kg + 1]);
                        float P1 = cvt2f(acc1[aa][m][8 * kg + 2], acc1[aa][m][8 * kg + 3]);
                        float P2 = cvt2f(acc1[aa][m][8 * kg + 4], acc1[aa][m][8 * kg + 5]);
                        float P3 = cvt2f(acc1[aa][m][8 * kg + 6], acc1[aa][m][8 * kg + 7]);
                        float q0 = __shfl_xor(P0, 32), q1 = __shfl_xor(P1, 32);
                        float q2 = __shfl_xor(P2, 32), q3 = __shfl_xor(P3, 32);
                        float w0 = hi ? q2 : P0, w1 = hi ? q3 : P1;
                        float w2 = hi ? P2 : q0, w3 = hi ? P3 : q1;
                        f16x8 oct = __builtin_bit_cast(f16x8, f32x4{w0, w1, w2, w3});
                        oct = __builtin_elementwise_max(oct + tb8, z8);
                        bf2[sp][m] = oct;
                    }
                }
            }
        }

        // ---- layers 2 (64 MFMA) + 3, in two a'-halves ----
        float s0 = 0.f, s1 = 0.f;
#pragma unroll
        for (int hf = 0; hf < 2; ++hf) {
            f32x16 acc2[2][2];
#pragma unroll
            for (int sp = 0; sp < 8; ++sp)
#pragma unroll
                for (int aa = 0; aa < 2; ++aa) {
                    f16x8 Af = W2a[((hf * 2 + aa) * 8 + sp) * 64 + l];
#pragma unroll
                    for (int m = 0; m < 2; ++m) {
                        if (sp == 0) acc2[aa][m] = MFMA32(Af, bf2[sp][m], zc16);
                        else         acc2[aa][m] = MFMA32(Af, bf2[sp][m], acc2[aa][m]);
                    }
                }
#pragma unroll
            for (int aa = 0; aa < 2; ++aa) {
                int a = hf * 2 + aa;
#pragma unroll
                for (int m = 0; m < 2; ++m) {
                    float acc = 0.f;
#pragma unroll
                    for (int q = 0; q < 8; ++q) {
                        f16x2 h2 = __builtin_bit_cast(f16x2,
                            __builtin_amdgcn_cvt_pkrtz(acc2[aa][m][2 * q], acc2[aa][m][2 * q + 1]));
                        f16x2 e = __builtin_elementwise_max(h2 + b2p[a][q], z2);
                        acc = __builtin_amdgcn_fdot2(e, w3p[a][q], acc, false);
                    }
                    if (m == 0) s0 += acc; else s1 += acc;
                }
            }
        }

        // cross-half reduce (rows with the other hi) and full-wave store
        s0 += __shfl_xor(s0, 32);
        s1 += __shfl_xor(s1, 32);
        size_t base = ((size_t)(b * N + ibase + il)) * N + jbase;
        out[base + 32 * hi + c] = (hi ? s1 : s0) + b3v;
    }
}

extern "C" void kernel_launch(void* const* d_in, const int* in_sizes, int n_in,
                              void* d_out, int out_size, void* d_ws, size_t ws_size,
                              hipStream_t stream) {
    const float* x  = (const float*)d_in[0];
    const float* y  = (const float*)d_in[1];
    const float* t  = (const float*)d_in[2];
    const float* W1 = (const float*)d_in[3];
    const float* b1 = (const float*)d_in[4];
    const float* W2 = (const float*)d_in[5];
    const float* b2 = (const float*)d_in[6];
    const float* W3 = (const float*)d_in[7];
    const float* b3 = (const float*)d_in[8];
    float* out = (float*)d_out;

    dim3 grid(8, 16, 4);   // (j-tiles of 64, i-tiles of 32, batch)
    dim3 block(256);
    pairmlp_kernel<<<grid, block, 0, stream>>>(x, y, t, W1, b1, W2, b2, W3, b3, out);
}